// Round 6
// baseline (88.638 us; speedup 1.0000x reference)
//
#include <hip/hip_runtime.h>
#include <hip/hip_bf16.h>

// out[n,h,i,j] = logits[i][ clamp(j-i+512, 1, 1023) ],  logits = Q @ R  (per n,h)
// n=4 h=16 L=1024 d=64, table width 1025.
//
// R6 = R5 + pre-transposed bf16 R table in d_ws (isolated change):
//   - lpb_pret: Rt[h][t][k] = bf16(R[h][k][t])  (2.1 MB, one-time per launch)
//   - GEMM B-fragments: two 16B vector loads/tile (was 16 scalar loads + 16 cvt)
//   - everything else identical to R5 (swap-MFMA, b128 LDS, nt stores, 256thr/(256,2))

#define NH 16
#define LQ 1024
#define DD 64
#define TT 1025
#define MAXP 512
#define PADF 4
#define LSTRIDE 1036   // 16*1036*4 = 66.3 KB -> 2 blocks/CU

typedef float f32x4 __attribute__((ext_vector_type(4)));
typedef short s16x8 __attribute__((ext_vector_type(8)));

__device__ __forceinline__ short f2bf(float f) {
    __hip_bfloat16 h = __float2bfloat16(f);   // RNE
    return __builtin_bit_cast(short, h);
}

// Rt[h][t][k] = bf16(R[h][k][t]); grid (ceil(1025/256)=5, h*8+kb=128)
__global__ __launch_bounds__(256) void lpb_pret(const float* __restrict__ R,
                                                short* __restrict__ Rt) {
    const int t = blockIdx.x * 256 + threadIdx.x;
    if (t >= TT) return;
    const int hk = blockIdx.y;
    const int h = hk >> 3, kb = hk & 7;
    const float* rp = R + (size_t)(h * DD + kb * 8) * TT + t;
    s16x8 v;
    #pragma unroll
    for (int r = 0; r < 8; ++r) v[r] = f2bf(rp[(size_t)r * TT]);
    *(s16x8*)(Rt + (size_t)(h * TT + t) * DD + kb * 8) = v;
}

// Writer helper: D = wave-uniform misalignment ((512 - i) & 3), compile-time.
template<int D>
__device__ __forceinline__ void write_chunks(const float* __restrict__ lrow,
                                             float p1, float p2,
                                             int i, int l, float* __restrict__ orow) {
    #pragma unroll
    for (int c = 0; c < 4; ++c) {
        const int j0 = c * 256 + 4 * l;
        const int t0 = j0 - i + MAXP;
        int colA = PADF + t0 - D;                 // = PADF + (t0 & ~3)
        colA = colA < 0 ? 0 : (colA > PADF + LQ ? PADF + LQ : colA);  // clamped lanes: value unused
        f32x4 A = *(const f32x4*)(lrow + colA);
        f32x4 B = {0.f, 0.f, 0.f, 0.f};
        if (D) B = *(const f32x4*)(lrow + colA + 4);
        f32x4 v;
        #pragma unroll
        for (int e = 0; e < 4; ++e) {
            const int t = t0 + e;
            const float in = (D + e < 4) ? A[D + e] : B[D + e - 4];
            v[e] = t < 1 ? p1 : (t > LQ - 1 ? p2 : in);
        }
        __builtin_nontemporal_store(v, (f32x4*)(orow + j0));
    }
}

// grid (ib=64, nh=64), block 256 = 4 waves; block = 16 i-rows x all 1024 t.
template<bool PRET>
__global__ __launch_bounds__(256, 2) void lpb_fused(const float* __restrict__ Q,
                                                    const float* __restrict__ R,
                                                    const short* __restrict__ Rt,
                                                    float* __restrict__ out) {
    __shared__ float lg[16][LSTRIDE];

    const int ib  = blockIdx.x;
    const int nh  = blockIdx.y;
    const int h   = nh & (NH - 1);
    const int tid = threadIdx.x;
    const int w   = tid >> 6, l = tid & 63;
    const int n   = l & 15, g = l >> 4;
    const int ibase = ib * 16;

    // Q fragment (op1/B of swapped MFMA): lane (n,g) holds Q[ibase+n][kh*32 + 8g + r]
    const float* qrow = Q + ((size_t)nh * LQ + (ibase + n)) * DD + 8 * g;
    s16x8 qf[2];
    #pragma unroll
    for (int kh = 0; kh < 2; ++kh) {
        f32x4 a = *(const f32x4*)(qrow + kh * 32);
        f32x4 b = *(const f32x4*)(qrow + kh * 32 + 4);
        #pragma unroll
        for (int r = 0; r < 4; ++r) { qf[kh][r] = f2bf(a[r]); qf[kh][4 + r] = f2bf(b[r]); }
    }

    // GEMM: wave w covers t in [256w, 256w+256), 16 tiles of 16 t, K=64
    const float* rbase = R + (size_t)(h * DD + 8 * g) * TT;
    #pragma unroll 4
    for (int mt = 0; mt < 16; ++mt) {
        const int tb = w * 256 + mt * 16;
        s16x8 rf0, rf1;   // A: lane (n,g) holds R[h][k][tb+n], k = 8g+r (+32)
        if (PRET) {
            const short* rp = Rt + (size_t)(h * TT + tb + n) * DD + 8 * g;
            rf0 = *(const s16x8*)rp;          // k = 8g..8g+7
            rf1 = *(const s16x8*)(rp + 32);   // k = 32+8g..32+8g+7
        } else {
            const float* rc = rbase + tb + n;
            #pragma unroll
            for (int r = 0; r < 8; ++r) {
                rf0[r] = f2bf(rc[(size_t)r * TT]);
                rf1[r] = f2bf(rc[(size_t)(32 + r) * TT]);
            }
        }
        f32x4 acc = (f32x4){0.f, 0.f, 0.f, 0.f};
        acc = __builtin_amdgcn_mfma_f32_16x16x32_bf16(rf0, qf[0], acc, 0, 0, 0);
        acc = __builtin_amdgcn_mfma_f32_16x16x32_bf16(rf1, qf[1], acc, 0, 0, 0);
        // D: col = n -> i-local, row = 4g+s -> t-local: one aligned b128 write
        *(f32x4*)&lg[n][PADF + tb + 4 * g] = acc;
    }
    __syncthreads();

    // writer: wave w emits rows 4w..4w+3 as full aligned 4KB rows (nt stores)
    #pragma unroll
    for (int rr = 0; rr < 4; ++rr) {
        const int il = 4 * w + rr;
        const int i  = ibase + il;
        const float* lrow = &lg[il][0];
        const float p1 = lrow[PADF + 1];          // left clamp constant
        const float p2 = lrow[PADF + LQ - 1];     // right clamp constant
        float* orow = out + ((size_t)nh * LQ + i) * LQ;
        switch ((MAXP - i) & 3) {                 // row-uniform shift
            case 0: write_chunks<0>(lrow, p1, p2, i, l, orow); break;
            case 1: write_chunks<1>(lrow, p1, p2, i, l, orow); break;
            case 2: write_chunks<2>(lrow, p1, p2, i, l, orow); break;
            default: write_chunks<3>(lrow, p1, p2, i, l, orow); break;
        }
    }
}

extern "C" void kernel_launch(void* const* d_in, const int* in_sizes, int n_in,
                              void* d_out, int out_size, void* d_ws, size_t ws_size,
                              hipStream_t stream) {
    const float* Q = (const float*)d_in[0];
    const float* R = (const float*)d_in[1];
    float* out = (float*)d_out;

    const size_t RT_BYTES = (size_t)NH * TT * DD * sizeof(short);  // 2.1 MB
    if (ws_size >= RT_BYTES) {
        short* Rt = (short*)d_ws;
        lpb_pret<<<dim3(5, NH * 8), 256, 0, stream>>>(R, Rt);
        lpb_fused<true><<<dim3(64, 64), 256, 0, stream>>>(Q, R, Rt, out);
    } else {
        lpb_fused<false><<<dim3(64, 64), 256, 0, stream>>>(Q, R, nullptr, out);
    }
}

// Round 7
// 80.686 us; speedup vs baseline: 1.0986x; 1.0986x over previous
//
#include <hip/hip_runtime.h>
#include <hip/hip_bf16.h>

// out[n,h,i,j] = logits[i][ clamp(j-i+512, 1, 1023) ],  logits = Q @ R  (per n,h)
// n=4 h=16 L=1024 d=64, table width 1025.
//
// R7 = R5 + bf16 LDS (33 KB -> 4 blocks/CU) as the single isolated change.
//   - GEMM: direct R gathers (R6 showed pret table regresses), swapped-operand MFMA,
//     acc packed to 4x bf16, one conflict-free ds_write_b64 per tile
//   - writer: aligned b64-pair LDS reads + wave-uniform shift select, bf16->f32 via <<16,
//     nontemporal f32x4 output stores (full aligned 4KB rows)

#define NH 16
#define LQ 1024
#define DD 64
#define TT 1025
#define MAXP 512
#define PADS 4          // left pad in shorts (multiple of 4 keeps 8B alignment)
#define LSTRIDE2 1036   // shorts; row stride 2072 B -> 518 dwords, %32=6: conflict-free

typedef float f32x4 __attribute__((ext_vector_type(4)));
typedef short s16x4 __attribute__((ext_vector_type(4)));
typedef short s16x8 __attribute__((ext_vector_type(8)));

__device__ __forceinline__ short f2bf(float f) {
    __hip_bfloat16 h = __float2bfloat16(f);   // RNE
    return __builtin_bit_cast(short, h);
}
__device__ __forceinline__ float bf2f(short s) {
    return __builtin_bit_cast(float, ((unsigned)(unsigned short)s) << 16);
}

// Writer helper: D = wave-uniform misalignment ((512 - i) & 3), compile-time.
template<int D>
__device__ __forceinline__ void write_chunks(const unsigned short* __restrict__ lrow,
                                             float p1, float p2,
                                             int i, int l, float* __restrict__ orow) {
    #pragma unroll
    for (int c = 0; c < 4; ++c) {
        const int j0 = c * 256 + 4 * l;
        const int t0 = j0 - i + MAXP;
        int colA = PADS + t0 - D;                 // = PADS + (t0 & ~3), 8B aligned
        colA = colA < 0 ? 0 : (colA > PADS + LQ ? PADS + LQ : colA);  // clamped lanes: value unused
        s16x4 A = *(const s16x4*)(lrow + colA);
        s16x4 B = {0, 0, 0, 0};
        if (D) B = *(const s16x4*)(lrow + colA + 4);
        f32x4 v;
        #pragma unroll
        for (int e = 0; e < 4; ++e) {
            const int t = t0 + e;
            const float in = bf2f((D + e < 4) ? A[D + e] : B[D + e - 4]);
            v[e] = t < 1 ? p1 : (t > LQ - 1 ? p2 : in);
        }
        __builtin_nontemporal_store(v, (f32x4*)(orow + j0));
    }
}

// grid (ib=64, nh=64), block 256 = 4 waves; block = 16 i-rows x all 1024 t.
__global__ __launch_bounds__(256, 4) void lpb_fused(const float* __restrict__ Q,
                                                    const float* __restrict__ R,
                                                    float* __restrict__ out) {
    __shared__ unsigned short lg[16][LSTRIDE2];   // bf16 logits, 33.2 KB

    const int ib  = blockIdx.x;
    const int nh  = blockIdx.y;
    const int h   = nh & (NH - 1);
    const int tid = threadIdx.x;
    const int w   = tid >> 6, l = tid & 63;
    const int n   = l & 15, g = l >> 4;
    const int ibase = ib * 16;

    // Q fragment (op1/B of swapped MFMA): lane (n,g) holds Q[ibase+n][kh*32 + 8g + r]
    const float* qrow = Q + ((size_t)nh * LQ + (ibase + n)) * DD + 8 * g;
    s16x8 qf[2];
    #pragma unroll
    for (int kh = 0; kh < 2; ++kh) {
        f32x4 a = *(const f32x4*)(qrow + kh * 32);
        f32x4 b = *(const f32x4*)(qrow + kh * 32 + 4);
        #pragma unroll
        for (int r = 0; r < 4; ++r) { qf[kh][r] = f2bf(a[r]); qf[kh][4 + r] = f2bf(b[r]); }
    }

    // GEMM: wave w covers t in [256w, 256w+256), 16 tiles of 16 t, K=64
    const float* rbase = R + (size_t)(h * DD + 8 * g) * TT;
    #pragma unroll 4
    for (int mt = 0; mt < 16; ++mt) {
        const int tb = w * 256 + mt * 16;
        const float* rc = rbase + tb + n;
        s16x8 rf0, rf1;   // A: lane (n,g) holds R[h][8g+r][tb+n]  (row = t-local = n)
        #pragma unroll
        for (int r = 0; r < 8; ++r) {
            rf0[r] = f2bf(rc[(size_t)r * TT]);
            rf1[r] = f2bf(rc[(size_t)(32 + r) * TT]);
        }
        f32x4 acc = (f32x4){0.f, 0.f, 0.f, 0.f};
        acc = __builtin_amdgcn_mfma_f32_16x16x32_bf16(rf0, qf[0], acc, 0, 0, 0);
        acc = __builtin_amdgcn_mfma_f32_16x16x32_bf16(rf1, qf[1], acc, 0, 0, 0);
        // D: col = n -> i-local row, row = 4g+s -> t = tb+4g+s: pack to bf16, b64 write
        s16x4 hv;
        #pragma unroll
        for (int s = 0; s < 4; ++s) hv[s] = f2bf(acc[s]);
        *(s16x4*)&lg[n][PADS + tb + 4 * g] = hv;
    }
    __syncthreads();

    // writer: wave w emits rows 4w..4w+3 as full aligned 4KB rows (nt stores)
    #pragma unroll
    for (int rr = 0; rr < 4; ++rr) {
        const int il = 4 * w + rr;
        const int i  = ibase + il;
        const unsigned short* lrow = &lg[il][0];
        const float p1 = bf2f(lrow[PADS + 1]);          // left clamp constant
        const float p2 = bf2f(lrow[PADS + LQ - 1]);     // right clamp constant
        float* orow = out + ((size_t)nh * LQ + i) * LQ;
        switch ((MAXP - i) & 3) {                       // row-uniform shift
            case 0: write_chunks<0>(lrow, p1, p2, i, l, orow); break;
            case 1: write_chunks<1>(lrow, p1, p2, i, l, orow); break;
            case 2: write_chunks<2>(lrow, p1, p2, i, l, orow); break;
            default: write_chunks<3>(lrow, p1, p2, i, l, orow); break;
        }
    }
}

extern "C" void kernel_launch(void* const* d_in, const int* in_sizes, int n_in,
                              void* d_out, int out_size, void* d_ws, size_t ws_size,
                              hipStream_t stream) {
    const float* Q = (const float*)d_in[0];
    const float* R = (const float*)d_in[1];
    float* out = (float*)d_out;

    lpb_fused<<<dim3(64, 64), 256, 0, stream>>>(Q, R, out);
}